// Round 6
// baseline (677.803 us; speedup 1.0000x reference)
//
#include <hip/hip_runtime.h>

// MLA forward. Inputs f32, internal bf16 MFMA 16x16x32, output f32.
// R6: k_attn latency hiding — __launch_bounds__(256,2) for a 256-VGPR budget,
// K-tile register prefetch (kt+1) + early V-fragment loads. Rest unchanged.

typedef __attribute__((ext_vector_type(8))) short short8;
typedef __attribute__((ext_vector_type(4))) float floatx4;
typedef unsigned short u16;
typedef unsigned int u32;

__device__ __forceinline__ float bf2f(u16 u){ u32 x=((u32)u)<<16; return __builtin_bit_cast(float,x); }
__device__ __forceinline__ u16 f2bf(float f){ u32 x=__builtin_bit_cast(u32,f); return (u16)((x + 0x7fffu + ((x>>16)&1u))>>16); }

__device__ __forceinline__ floatx4 mfma16(short8 a, short8 b, floatx4 c){
  return __builtin_amdgcn_mfma_f32_16x16x32_bf16(a,b,c,0,0,0);
}

// async global->LDS, 16B per lane. LDS dest = wave-uniform base + lane*16.
__device__ __forceinline__ void gl_lds16(const u16* g, u16* l){
  __builtin_amdgcn_global_load_lds((const __attribute__((address_space(1))) void*)g,
                                   (__attribute__((address_space(3))) void*)l, 16, 0, 0);
}

// ---------- f32 -> bf16 elementwise (for x) ----------
__global__ __launch_bounds__(256)
void k_f2b(const float* __restrict__ in, u16* __restrict__ out, size_t n){
  size_t i = ((size_t)blockIdx.x*256 + threadIdx.x)*4;
  if(i >= n) return;
  float4 v = *(const float4*)(in + i);
  out[i+0] = f2bf(v.x); out[i+1] = f2bf(v.y); out[i+2] = f2bf(v.z); out[i+3] = f2bf(v.w);
}

// ---------- transpose + convert: f32 [K,N] -> bf16 [N,K] ----------
__global__ void k_transpose(const float* __restrict__ in, u16* __restrict__ out, int K, int N){
  __shared__ u16 tile[32][33];
  const int kb = blockIdx.y*32, nb = blockIdx.x*32;
  const int tx = threadIdx.x, ty = threadIdx.y;
#pragma unroll
  for(int i=0;i<4;i++) tile[ty+i*8][tx] = f2bf(in[(size_t)(kb+ty+i*8)*N + nb + tx]);
  __syncthreads();
#pragma unroll
  for(int i=0;i<4;i++) out[(size_t)(nb+ty+i*8)*K + kb + tx] = tile[tx][ty+i*8];
}

// ---------- rope table (fp64 for large-angle accuracy) ----------
__global__ void k_rope_table(float* __restrict__ cosT, float* __restrict__ sinT){
  int idx = blockIdx.x*256 + threadIdx.x;
  if(idx >= 2048*64) return;
  int p = idx>>6, i = idx&63;
  double freq = pow(10000.0, -(double)(2*i)/128.0) * 40.0;
  float ff = (float)freq;
  float ang = (float)((double)p * (double)ff);
  cosT[idx] = (float)cos((double)ang);
  sinT[idx] = (float)sin((double)ang);
}

// ---------- GEMM: A[M,K] bf16 @ Bt[N,K] bf16 -> C[M,N] (bf16 or f32) ----------
template<int OUTF32>
__global__ __launch_bounds__(256)
void k_gemm_bt(const u16* __restrict__ A, const u16* __restrict__ Bt, void* __restrict__ Cout,
               int M, int N, int K){
  __shared__ __align__(16) u16 lsA[128*32];
  __shared__ __align__(16) u16 lsB[128*32];
  const int t = threadIdx.x;
  const int m0 = blockIdx.y*128, n0 = blockIdx.x*128;
  const int wv = t>>6, ln = t&63;
  const int wr = (wv>>1)*64, wc = (wv&1)*64;
  const int fr = ln&15, kh = (ln>>4)*8;
  const int srow = wv*16 + (ln>>2), sk = (ln&3)*8;
  const u16* Ag = A + (size_t)(m0 + srow)*K + sk;
  const u16* Bg = Bt + (size_t)(n0 + srow)*K + sk;
  u16* lA0 = &lsA[wv*512];
  u16* lB0 = &lsB[wv*512];
  floatx4 acc[4][4];
#pragma unroll
  for(int i=0;i<4;i++)
#pragma unroll
    for(int j=0;j<4;j++) acc[i][j] = (floatx4){0.f,0.f,0.f,0.f};
  for(int k0=0;k0<K;k0+=32){
    __syncthreads();
    gl_lds16(Ag + k0,              lA0);
    gl_lds16(Ag + (size_t)64*K + k0, lA0 + 2048);
    gl_lds16(Bg + k0,              lB0);
    gl_lds16(Bg + (size_t)64*K + k0, lB0 + 2048);
    __syncthreads();
    short8 af[4], bf[4];
#pragma unroll
    for(int i=0;i<4;i++) af[i] = *(const short8*)&lsA[(wr + i*16 + fr)*32 + kh];
#pragma unroll
    for(int i=0;i<4;i++) bf[i] = *(const short8*)&lsB[(wc + i*16 + fr)*32 + kh];
#pragma unroll
    for(int mi=0;mi<4;mi++)
#pragma unroll
      for(int ni=0;ni<4;ni++) acc[mi][ni] = mfma16(af[mi], bf[ni], acc[mi][ni]);
  }
  const int r0 = (ln>>4)*4, c0 = ln&15;
#pragma unroll
  for(int mi=0;mi<4;mi++)
#pragma unroll
    for(int ni=0;ni<4;ni++){
      const int row = m0 + wr + mi*16 + r0;
      const int col = n0 + wc + ni*16 + c0;
#pragma unroll
      for(int r=0;r<4;r++){
        float v = acc[mi][ni][r];
        if(OUTF32) ((float*)Cout)[(size_t)(row+r)*N + col] = v;
        else       ((u16*)Cout)[(size_t)(row+r)*N + col] = f2bf(v);
      }
    }
}

// ---------- layernorm(kv[:512]) -> bf16 ; rope(kv[512:640]) -> k_pe bf16 ----------
__global__ __launch_bounds__(256)
void k_ln_rope(const float* __restrict__ kv, const float* __restrict__ scale,
               const int* __restrict__ pid, const float* __restrict__ cosT,
               const float* __restrict__ sinT, u16* __restrict__ kv_cn, u16* __restrict__ k_pe){
  const int tok = blockIdx.x;
  const int t = threadIdx.x;
  const float* row = kv + (size_t)tok*640;
  float v0 = row[2*t], v1 = row[2*t+1];
  float s = v0+v1, ss = v0*v0+v1*v1;
#pragma unroll
  for(int off=32; off>=1; off>>=1){ s += __shfl_xor(s,off); ss += __shfl_xor(ss,off); }
  __shared__ float red[8];
  if((t&63)==0){ red[t>>6]=s; red[4+(t>>6)]=ss; }
  __syncthreads();
  float S4 = red[0]+red[1]+red[2]+red[3];
  float SS4 = red[4]+red[5]+red[6]+red[7];
  float mean = S4*(1.f/512.f);
  float var = SS4*(1.f/512.f) - mean*mean;
  float inv = rsqrtf(var + 1e-5f);
  kv_cn[(size_t)tok*512 + 2*t]   = f2bf((v0-mean)*inv*scale[2*t]);
  kv_cn[(size_t)tok*512 + 2*t+1] = f2bf((v1-mean)*inv*scale[2*t+1]);
  if(t < 128){
    const int sidx = tok & 2047;
    const int p = pid[sidx];
    const int i = t>>1;
    float c = cosT[p*64+i], sn = sinT[p*64+i];
    float xr = row[512+2*i], xi = row[512+2*i+1];
    float val = (t&1) ? (xr*sn + xi*c) : (xr*c - xi*sn);
    k_pe[(size_t)tok*128 + t] = f2bf(val);
  }
}

// ---------- q: copy nope, rope pe; fold scale*log2e; layout [B,H,S,256] ----------
__global__ __launch_bounds__(256)
void k_q_rope(const u16* __restrict__ q_raw, const int* __restrict__ pid,
              const float* __restrict__ cosT, const float* __restrict__ sinT,
              u16* __restrict__ q_fin){
  const float QS = (float)(0.08838834764831845 * 1.4426950408889634); // /sqrt(128) * log2(e)
  const int tok = blockIdx.x;
  const int b = tok>>11, sidx = tok&2047;
  const int t = threadIdx.x;
  const int p = pid[sidx];
  for(int h=0; h<16; h++){
    const u16* src = q_raw + (size_t)tok*4096 + h*256;
    float val;
    if(t < 128) val = bf2f(src[t]);
    else {
      int d = t-128, i = d>>1;
      float c = cosT[p*64+i], sn = sinT[p*64+i];
      float xr = bf2f(src[128+2*i]), xi = bf2f(src[128+2*i+1]);
      val = (d&1) ? (xr*sn + xi*c) : (xr*c - xi*sn);
    }
    q_fin[(((size_t)(b*16 + h))*2048 + sidx)*256 + t] = f2bf(val*QS);
  }
}

// ---------- k_full[b][kvh][s][256] = concat(k_nope, k_pe) ----------
__global__ __launch_bounds__(256)
void k_build_k(const u16* __restrict__ kvb, const u16* __restrict__ k_pe, u16* __restrict__ k_full){
  const int tok = blockIdx.x;
  const int b = tok>>11, sidx = tok&2047;
  const int t = threadIdx.x;
  for(int kh=0; kh<8; kh++){
    u16 v = (t<128) ? kvb[(size_t)tok*2048 + kh*256 + t]
                    : k_pe[(size_t)tok*128 + (t-128)];
    k_full[(((size_t)(b*8 + kh))*2048 + sidx)*256 + t] = v;
  }
}

// ---------- v_t[b][kvh][hd][s] from kvb v-part ----------
__global__ void k_v_t(const u16* __restrict__ kvb, u16* __restrict__ v_t){
  __shared__ u16 tile[32][33];
  const int sb = blockIdx.x*32, hb = blockIdx.y*32;
  const int bk = blockIdx.z;
  const int b = bk>>3, kh = bk&7;
  const int tx = threadIdx.x, ty = threadIdx.y;
#pragma unroll
  for(int i=0;i<4;i++){
    int sidx = sb + ty + i*8;
    tile[ty+i*8][tx] = kvb[((size_t)(b*2048 + sidx))*2048 + kh*256 + 128 + hb + tx];
  }
  __syncthreads();
#pragma unroll
  for(int i=0;i<4;i++){
    int hd = hb + ty + i*8;
    v_t[((size_t)bk*128 + hd)*2048 + sb + tx] = tile[tx][ty+i*8];
  }
}

// ---------- flash attention, S^T layout, register-prefetched K + early V ----------
// __launch_bounds__(256,2): declare 2 waves/EU (= our actual 2 blocks/CU) so
// the VGPR budget is 256 — kpre[8]+vv[16] live across compute WITHOUT spill.
__global__ __launch_bounds__(256, 2)
void k_attn(const u16* __restrict__ q_fin, const u16* __restrict__ k_full,
            const u16* __restrict__ v_t, u16* __restrict__ attn){
  __shared__ __align__(16) u16 lsK[64*264];   // 33792 B
  __shared__ __align__(16) u16 lsP[4*16*72];  // 9216 B per-wave P
  const int pr = blockIdx.x, h = blockIdx.y, b = blockIdx.z;
  const int kvh = h>>1;
  const int t = threadIdx.x, wv = t>>6, ln = t&63;
  const int fq = ln&15, g = ln>>4;
  const u16* kbase = k_full + ((size_t)(b*8 + kvh))*2048*256;
  const u16* vbase = v_t + ((size_t)(b*8 + kvh))*128*2048;
  u16* Pw = &lsP[wv*16*72];
  const int tr = t>>5, tc = (t&31)*8;   // staging: row tr+8i, col tc (u16 units)

  for(int half=0; half<2; half++){
    const int qt = half ? (31-pr) : pr;
    short8 qf[8];
    const u16* qb = q_fin + (((size_t)(b*16 + h))*2048 + qt*64 + wv*16 + fq)*256;
#pragma unroll
    for(int c=0;c<8;c++) qf[c] = *(const short8*)(qb + c*32 + g*8);
    floatx4 oacc[8];
#pragma unroll
    for(int i=0;i<8;i++) oacc[i] = (floatx4){0.f,0.f,0.f,0.f};
    float mprev = -3e38f, lsum = 0.f;

    // prologue: prefetch K tile 0 into registers
    uint4 kpre[8];
    {
      const u16* kg = kbase + (size_t)tr*256 + tc;
#pragma unroll
      for(int i=0;i<8;i++) kpre[i] = *(const uint4*)(kg + (size_t)i*2048);
    }

    for(int kt=0; kt<=qt; kt++){
      __syncthreads();   // prev-iteration lsK reads done
#pragma unroll
      for(int i=0;i<8;i++) *(uint4*)&lsK[(tr + i*8)*264 + tc] = kpre[i];
      __syncthreads();   // lsK ready

      // issue next K tile prefetch (covered by this iteration's compute)
      if(kt < qt){
        const u16* kg = kbase + (size_t)((kt+1)*64 + tr)*256 + tc;
#pragma unroll
        for(int i=0;i<8;i++) kpre[i] = *(const uint4*)(kg + (size_t)i*2048);
      }
      // issue all V fragment loads for THIS tile early (consumed in PV below)
      short8 vv[16];
#pragma unroll
      for(int cc=0;cc<2;cc++)
#pragma unroll
        for(int hs=0;hs<8;hs++)
          vv[cc*8+hs] = *(const short8*)(vbase + (size_t)(hs*16 + fq)*2048 + kt*64 + cc*32 + g*8);

      // S^T = K · Q^T : rows kv, cols q
      floatx4 sc[4];
#pragma unroll
      for(int ns=0;ns<4;ns++) sc[ns] = (floatx4){0.f,0.f,0.f,0.f};
#pragma unroll
      for(int ns=0;ns<4;ns++){
        const u16* kr = &lsK[(ns*16 + fq)*264 + g*8];
#pragma unroll
        for(int c=0;c<8;c++){
          short8 kf = *(const short8*)(kr + c*32);
          sc[ns] = mfma16(kf, qf[c], sc[ns]);
        }
      }
      if(kt == qt){  // diagonal tile: mask kv > q
        const int qloc = wv*16 + fq;
#pragma unroll
        for(int ns=0;ns<4;ns++)
#pragma unroll
          for(int r=0;r<4;r++)
            if(ns*16 + g*4 + r > qloc) sc[ns][r] = -1e30f;
      }
      // per-q (column) max
      float mloc = -3e38f;
#pragma unroll
      for(int ns=0;ns<4;ns++)
#pragma unroll
        for(int r=0;r<4;r++) mloc = fmaxf(mloc, sc[ns][r]);
      mloc = fmaxf(mloc, __shfl_xor(mloc, 16));
      mloc = fmaxf(mloc, __shfl_xor(mloc, 32));
      const float mn = fmaxf(mprev, mloc);
      const float alpha = exp2f(mprev - mn);
      float ps = 0.f;
#pragma unroll
      for(int ns=0;ns<4;ns++)
#pragma unroll
        for(int r=0;r<4;r++){
          float p = exp2f(sc[ns][r] - mn);
          sc[ns][r] = p;
          ps += p;
        }
      ps += __shfl_xor(ps, 16);
      ps += __shfl_xor(ps, 32);
      lsum = lsum*alpha + ps;
      mprev = mn;

      // P -> per-wave LDS in A-layout: row q=fq, cols kv
#pragma unroll
      for(int ns=0;ns<4;ns++){
        u32 p01 = (u32)f2bf(sc[ns][0]) | ((u32)f2bf(sc[ns][1])<<16);
        u32 p23 = (u32)f2bf(sc[ns][2]) | ((u32)f2bf(sc[ns][3])<<16);
        uint2 pk; pk.x = p01; pk.y = p23;
        *(uint2*)&Pw[fq*72 + ns*16 + g*4] = pk;
      }
      // rescale O rows (row q = g*4+r)
      float alphaO[4];
#pragma unroll
      for(int r=0;r<4;r++) alphaO[r] = __shfl(alpha, g*4 + r);
#pragma unroll
      for(int hs=0;hs<8;hs++)
#pragma unroll
        for(int r=0;r<4;r++) oacc[hs][r] *= alphaO[r];
      __builtin_amdgcn_s_waitcnt(0xC07F);  // lgkmcnt(0): P visible to own wave

      // O += P · V  (V already in registers)
#pragma unroll
      for(int cc=0;cc<2;cc++){
        short8 pa = *(const short8*)&Pw[fq*72 + cc*32 + g*8];
#pragma unroll
        for(int hs=0;hs<8;hs++)
          oacc[hs] = mfma16(pa, vv[cc*8+hs], oacc[hs]);
      }
    }
    const float inv = 1.f / lsum;
    float invO[4];
#pragma unroll
    for(int r=0;r<4;r++) invO[r] = __shfl(inv, g*4 + r);
#pragma unroll
    for(int hs=0;hs<8;hs++)
#pragma unroll
      for(int r=0;r<4;r++){
        const int qi = qt*64 + wv*16 + g*4 + r;
        attn[(((size_t)(b*2048 + qi))*16 + h)*128 + hs*16 + fq] = f2bf(oacc[hs][r]*invO[r]);
      }
  }
}

extern "C" void kernel_launch(void* const* d_in, const int* in_sizes, int n_in,
                              void* d_out, int out_size, void* d_ws, size_t ws_size,
                              hipStream_t stream){
  const float* x    = (const float*)d_in[0];
  const float* wq   = (const float*)d_in[1];
  const float* wkva = (const float*)d_in[2];
  const float* kvsc = (const float*)d_in[3];
  const float* wkvb = (const float*)d_in[4];
  const float* wo   = (const float*)d_in[5];
  const int* pid  = (const int*)d_in[7];
  float* out = (float*)d_out;

  char* w = (char*)d_ws;
  size_t off = 0;
  auto alloc = [&](size_t bytes)->void*{
    void* p = (void*)(w + off);
    off += (bytes + 255) & ~(size_t)255;
    return p;
  };
  u16*   x_bf   = (u16*)alloc((size_t)4096*2048*2);
  u16*   wq_t   = (u16*)alloc((size_t)4096*2048*2);
  u16*   wkva_t = (u16*)alloc((size_t)640*2048*2);
  u16*   wkvb_t = (u16*)alloc((size_t)2048*512*2);
  u16*   wo_t   = (u16*)alloc((size_t)2048*2048*2);
  float* cosT   = (float*)alloc((size_t)2048*64*4);
  float* sinT   = (float*)alloc((size_t)2048*64*4);
  u16*   q_raw  = (u16*)alloc((size_t)4096*4096*2);
  float* kvf    = (float*)alloc((size_t)4096*640*4);
  u16*   kv_cn  = (u16*)alloc((size_t)4096*512*2);
  u16*   k_pe   = (u16*)alloc((size_t)4096*128*2);
  u16*   kvb    = (u16*)alloc((size_t)4096*2048*2);
  u16*   q_fin  = (u16*)alloc((size_t)4096*4096*2);
  u16*   k_full = (u16*)alloc((size_t)2*8*2048*256*2);
  u16*   v_t    = (u16*)alloc((size_t)2*8*128*2048*2);
  u16*   attn   = (u16*)alloc((size_t)4096*2048*2);

  k_f2b<<<8192, 256, 0, stream>>>(x, x_bf, (size_t)4096*2048);
  k_transpose<<<dim3(128, 64), dim3(32,8), 0, stream>>>(wq,   wq_t,   2048, 4096);
  k_transpose<<<dim3(20,  64), dim3(32,8), 0, stream>>>(wkva, wkva_t, 2048, 640);
  k_transpose<<<dim3(64,  16), dim3(32,8), 0, stream>>>(wkvb, wkvb_t, 512,  2048);
  k_transpose<<<dim3(64,  64), dim3(32,8), 0, stream>>>(wo,   wo_t,   2048, 2048);
  k_rope_table<<<512, 256, 0, stream>>>(cosT, sinT);

  k_gemm_bt<0><<<dim3(32, 32), 256, 0, stream>>>(x_bf, wq_t, q_raw, 4096, 4096, 2048);
  k_gemm_bt<1><<<dim3(5,  32), 256, 0, stream>>>(x_bf, wkva_t, kvf, 4096, 640, 2048);
  k_ln_rope<<<4096, 256, 0, stream>>>(kvf, kvsc, pid, cosT, sinT, kv_cn, k_pe);
  k_gemm_bt<0><<<dim3(16, 32), 256, 0, stream>>>(kv_cn, wkvb_t, kvb, 4096, 2048, 512);
  k_q_rope<<<4096, 256, 0, stream>>>(q_raw, pid, cosT, sinT, q_fin);
  k_build_k<<<4096, 256, 0, stream>>>(kvb, k_pe, k_full);
  k_v_t<<<dim3(64, 4, 16), dim3(32,8), 0, stream>>>(kvb, v_t);
  k_attn<<<dim3(16, 16, 2), 256, 0, stream>>>(q_fin, k_full, v_t, attn);
  k_gemm_bt<1><<<dim3(16, 32), 256, 0, stream>>>(attn, wo_t, out, 4096, 2048, 2048);
}

// Round 7
// 600.497 us; speedup vs baseline: 1.1287x; 1.1287x over previous
//
#include <hip/hip_runtime.h>

// MLA forward. Inputs f32, internal bf16 MFMA 16x16x32, output f32.
// R7: k_attn body = R5 (register prefetch reverted — spilled twice).
// NEW: XCD-aware 1D grid swizzle so all blocks sharing one (b,kvh)'s K/V land
// on one XCD -> L2-resident K/V instead of 8x HBM refetch.

typedef __attribute__((ext_vector_type(8))) short short8;
typedef __attribute__((ext_vector_type(4))) float floatx4;
typedef unsigned short u16;
typedef unsigned int u32;

__device__ __forceinline__ float bf2f(u16 u){ u32 x=((u32)u)<<16; return __builtin_bit_cast(float,x); }
__device__ __forceinline__ u16 f2bf(float f){ u32 x=__builtin_bit_cast(u32,f); return (u16)((x + 0x7fffu + ((x>>16)&1u))>>16); }

__device__ __forceinline__ floatx4 mfma16(short8 a, short8 b, floatx4 c){
  return __builtin_amdgcn_mfma_f32_16x16x32_bf16(a,b,c,0,0,0);
}

// async global->LDS, 16B per lane. LDS dest = wave-uniform base + lane*16.
__device__ __forceinline__ void gl_lds16(const u16* g, u16* l){
  __builtin_amdgcn_global_load_lds((const __attribute__((address_space(1))) void*)g,
                                   (__attribute__((address_space(3))) void*)l, 16, 0, 0);
}

// ---------- f32 -> bf16 elementwise (for x) ----------
__global__ __launch_bounds__(256)
void k_f2b(const float* __restrict__ in, u16* __restrict__ out, size_t n){
  size_t i = ((size_t)blockIdx.x*256 + threadIdx.x)*4;
  if(i >= n) return;
  float4 v = *(const float4*)(in + i);
  out[i+0] = f2bf(v.x); out[i+1] = f2bf(v.y); out[i+2] = f2bf(v.z); out[i+3] = f2bf(v.w);
}

// ---------- transpose + convert: f32 [K,N] -> bf16 [N,K] ----------
__global__ void k_transpose(const float* __restrict__ in, u16* __restrict__ out, int K, int N){
  __shared__ u16 tile[32][33];
  const int kb = blockIdx.y*32, nb = blockIdx.x*32;
  const int tx = threadIdx.x, ty = threadIdx.y;
#pragma unroll
  for(int i=0;i<4;i++) tile[ty+i*8][tx] = f2bf(in[(size_t)(kb+ty+i*8)*N + nb + tx]);
  __syncthreads();
#pragma unroll
  for(int i=0;i<4;i++) out[(size_t)(nb+ty+i*8)*K + kb + tx] = tile[tx][ty+i*8];
}

// ---------- rope table (fp64 for large-angle accuracy) ----------
__global__ void k_rope_table(float* __restrict__ cosT, float* __restrict__ sinT){
  int idx = blockIdx.x*256 + threadIdx.x;
  if(idx >= 2048*64) return;
  int p = idx>>6, i = idx&63;
  double freq = pow(10000.0, -(double)(2*i)/128.0) * 40.0;
  float ff = (float)freq;
  float ang = (float)((double)p * (double)ff);
  cosT[idx] = (float)cos((double)ang);
  sinT[idx] = (float)sin((double)ang);
}

// ---------- GEMM: A[M,K] bf16 @ Bt[N,K] bf16 -> C[M,N] (bf16 or f32) ----------
template<int OUTF32>
__global__ __launch_bounds__(256)
void k_gemm_bt(const u16* __restrict__ A, const u16* __restrict__ Bt, void* __restrict__ Cout,
               int M, int N, int K){
  __shared__ __align__(16) u16 lsA[128*32];
  __shared__ __align__(16) u16 lsB[128*32];
  const int t = threadIdx.x;
  const int m0 = blockIdx.y*128, n0 = blockIdx.x*128;
  const int wv = t>>6, ln = t&63;
  const int wr = (wv>>1)*64, wc = (wv&1)*64;
  const int fr = ln&15, kh = (ln>>4)*8;
  const int srow = wv*16 + (ln>>2), sk = (ln&3)*8;
  const u16* Ag = A + (size_t)(m0 + srow)*K + sk;
  const u16* Bg = Bt + (size_t)(n0 + srow)*K + sk;
  u16* lA0 = &lsA[wv*512];
  u16* lB0 = &lsB[wv*512];
  floatx4 acc[4][4];
#pragma unroll
  for(int i=0;i<4;i++)
#pragma unroll
    for(int j=0;j<4;j++) acc[i][j] = (floatx4){0.f,0.f,0.f,0.f};
  for(int k0=0;k0<K;k0+=32){
    __syncthreads();
    gl_lds16(Ag + k0,              lA0);
    gl_lds16(Ag + (size_t)64*K + k0, lA0 + 2048);
    gl_lds16(Bg + k0,              lB0);
    gl_lds16(Bg + (size_t)64*K + k0, lB0 + 2048);
    __syncthreads();
    short8 af[4], bf[4];
#pragma unroll
    for(int i=0;i<4;i++) af[i] = *(const short8*)&lsA[(wr + i*16 + fr)*32 + kh];
#pragma unroll
    for(int i=0;i<4;i++) bf[i] = *(const short8*)&lsB[(wc + i*16 + fr)*32 + kh];
#pragma unroll
    for(int mi=0;mi<4;mi++)
#pragma unroll
      for(int ni=0;ni<4;ni++) acc[mi][ni] = mfma16(af[mi], bf[ni], acc[mi][ni]);
  }
  const int r0 = (ln>>4)*4, c0 = ln&15;
#pragma unroll
  for(int mi=0;mi<4;mi++)
#pragma unroll
    for(int ni=0;ni<4;ni++){
      const int row = m0 + wr + mi*16 + r0;
      const int col = n0 + wc + ni*16 + c0;
#pragma unroll
      for(int r=0;r<4;r++){
        float v = acc[mi][ni][r];
        if(OUTF32) ((float*)Cout)[(size_t)(row+r)*N + col] = v;
        else       ((u16*)Cout)[(size_t)(row+r)*N + col] = f2bf(v);
      }
    }
}

// ---------- layernorm(kv[:512]) -> bf16 ; rope(kv[512:640]) -> k_pe bf16 ----------
__global__ __launch_bounds__(256)
void k_ln_rope(const float* __restrict__ kv, const float* __restrict__ scale,
               const int* __restrict__ pid, const float* __restrict__ cosT,
               const float* __restrict__ sinT, u16* __restrict__ kv_cn, u16* __restrict__ k_pe){
  const int tok = blockIdx.x;
  const int t = threadIdx.x;
  const float* row = kv + (size_t)tok*640;
  float v0 = row[2*t], v1 = row[2*t+1];
  float s = v0+v1, ss = v0*v0+v1*v1;
#pragma unroll
  for(int off=32; off>=1; off>>=1){ s += __shfl_xor(s,off); ss += __shfl_xor(ss,off); }
  __shared__ float red[8];
  if((t&63)==0){ red[t>>6]=s; red[4+(t>>6)]=ss; }
  __syncthreads();
  float S4 = red[0]+red[1]+red[2]+red[3];
  float SS4 = red[4]+red[5]+red[6]+red[7];
  float mean = S4*(1.f/512.f);
  float var = SS4*(1.f/512.f) - mean*mean;
  float inv = rsqrtf(var + 1e-5f);
  kv_cn[(size_t)tok*512 + 2*t]   = f2bf((v0-mean)*inv*scale[2*t]);
  kv_cn[(size_t)tok*512 + 2*t+1] = f2bf((v1-mean)*inv*scale[2*t+1]);
  if(t < 128){
    const int sidx = tok & 2047;
    const int p = pid[sidx];
    const int i = t>>1;
    float c = cosT[p*64+i], sn = sinT[p*64+i];
    float xr = row[512+2*i], xi = row[512+2*i+1];
    float val = (t&1) ? (xr*sn + xi*c) : (xr*c - xi*sn);
    k_pe[(size_t)tok*128 + t] = f2bf(val);
  }
}

// ---------- q: copy nope, rope pe; fold scale*log2e; layout [B,H,S,256] ----------
__global__ __launch_bounds__(256)
void k_q_rope(const u16* __restrict__ q_raw, const int* __restrict__ pid,
              const float* __restrict__ cosT, const float* __restrict__ sinT,
              u16* __restrict__ q_fin){
  const float QS = (float)(0.08838834764831845 * 1.4426950408889634); // /sqrt(128) * log2(e)
  const int tok = blockIdx.x;
  const int b = tok>>11, sidx = tok&2047;
  const int t = threadIdx.x;
  const int p = pid[sidx];
  for(int h=0; h<16; h++){
    const u16* src = q_raw + (size_t)tok*4096 + h*256;
    float val;
    if(t < 128) val = bf2f(src[t]);
    else {
      int d = t-128, i = d>>1;
      float c = cosT[p*64+i], sn = sinT[p*64+i];
      float xr = bf2f(src[128+2*i]), xi = bf2f(src[128+2*i+1]);
      val = (d&1) ? (xr*sn + xi*c) : (xr*c - xi*sn);
    }
    q_fin[(((size_t)(b*16 + h))*2048 + sidx)*256 + t] = f2bf(val*QS);
  }
}

// ---------- k_full[b][kvh][s][256] = concat(k_nope, k_pe) ----------
__global__ __launch_bounds__(256)
void k_build_k(const u16* __restrict__ kvb, const u16* __restrict__ k_pe, u16* __restrict__ k_full){
  const int tok = blockIdx.x;
  const int b = tok>>11, sidx = tok&2047;
  const int t = threadIdx.x;
  for(int kh=0; kh<8; kh++){
    u16 v = (t<128) ? kvb[(size_t)tok*2048 + kh*256 + t]
                    : k_pe[(size_t)tok*128 + (t-128)];
    k_full[(((size_t)(b*8 + kh))*2048 + sidx)*256 + t] = v;
  }
}

// ---------- v_t[b][kvh][hd][s] from kvb v-part ----------
__global__ void k_v_t(const u16* __restrict__ kvb, u16* __restrict__ v_t){
  __shared__ u16 tile[32][33];
  const int sb = blockIdx.x*32, hb = blockIdx.y*32;
  const int bk = blockIdx.z;
  const int b = bk>>3, kh = bk&7;
  const int tx = threadIdx.x, ty = threadIdx.y;
#pragma unroll
  for(int i=0;i<4;i++){
    int sidx = sb + ty + i*8;
    tile[ty+i*8][tx] = kvb[((size_t)(b*2048 + sidx))*2048 + kh*256 + 128 + hb + tx];
  }
  __syncthreads();
#pragma unroll
  for(int i=0;i<4;i++){
    int hd = hb + ty + i*8;
    v_t[((size_t)bk*128 + hd)*2048 + sb + tx] = tile[tx][ty+i*8];
  }
}

// ---------- flash attention, S^T layout, XCD-swizzled 1D grid ----------
// 512 blocks. Group g=(b*8+kvh) has 32 blocks (16 pr x 2 heads); block id
// chosen so all of group g share (id % 8) -> same XCD under round-robin
// dispatch -> K/V stay L2-resident (4 MB/XCD working set).
__global__ __launch_bounds__(256)
void k_attn(const u16* __restrict__ q_fin, const u16* __restrict__ k_full,
            const u16* __restrict__ v_t, u16* __restrict__ attn){
  __shared__ __align__(16) u16 lsK[64*264];   // 33792 B
  __shared__ __align__(16) u16 lsP[4*16*72];  // 9216 B per-wave P
  // decode swizzled id: blk = hi*256 + i*8 + (g&7), hi = g>>3
  const int blk = blockIdx.x;
  const int g  = (blk>>8)*8 + (blk&7);   // 0..15 = b*8+kvh
  const int i  = (blk>>3)&31;            // 0..31 within group
  const int b  = g>>3, kvh = g&7;
  const int pr = i&15;
  const int h  = kvh*2 + (i>>4);
  const int t = threadIdx.x, wv = t>>6, ln = t&63;
  const int fq = ln&15, gq = ln>>4;
  const u16* kbase = k_full + ((size_t)(b*8 + kvh))*2048*256;
  const u16* vbase = v_t + ((size_t)(b*8 + kvh))*128*2048;
  u16* Pw = &lsP[wv*16*72];

  for(int half=0; half<2; half++){
    const int qt = half ? (31-pr) : pr;
    short8 qf[8];
    const u16* qb = q_fin + (((size_t)(b*16 + h))*2048 + qt*64 + wv*16 + fq)*256;
#pragma unroll
    for(int c=0;c<8;c++) qf[c] = *(const short8*)(qb + c*32 + gq*8);
    floatx4 oacc[8];
#pragma unroll
    for(int ii=0;ii<8;ii++) oacc[ii] = (floatx4){0.f,0.f,0.f,0.f};
    float mprev = -3e38f, lsum = 0.f;

    for(int kt=0; kt<=qt; kt++){
      __syncthreads();   // protect prev-iteration lsK reads
#pragma unroll
      for(int ii=0;ii<8;ii++){
        int c = t + ii*256, row = c>>5, col = (c&31)*8;
        *(uint4*)&lsK[row*264 + col] = *(const uint4*)(kbase + (size_t)(kt*64+row)*256 + col);
      }
      __syncthreads();

      // S^T = K · Q^T : rows kv, cols q
      floatx4 sc[4];
#pragma unroll
      for(int ns=0;ns<4;ns++) sc[ns] = (floatx4){0.f,0.f,0.f,0.f};
#pragma unroll
      for(int ns=0;ns<4;ns++){
        const u16* kr = &lsK[(ns*16 + fq)*264 + gq*8];
#pragma unroll
        for(int c=0;c<8;c++){
          short8 kf = *(const short8*)(kr + c*32);
          sc[ns] = mfma16(kf, qf[c], sc[ns]);
        }
      }
      if(kt == qt){  // diagonal tile: mask kv > q
        const int qloc = wv*16 + fq;
#pragma unroll
        for(int ns=0;ns<4;ns++)
#pragma unroll
          for(int r=0;r<4;r++)
            if(ns*16 + gq*4 + r > qloc) sc[ns][r] = -1e30f;
      }
      // per-q (column) max
      float mloc = -3e38f;
#pragma unroll
      for(int ns=0;ns<4;ns++)
#pragma unroll
        for(int r=0;r<4;r++) mloc = fmaxf(mloc, sc[ns][r]);
      mloc = fmaxf(mloc, __shfl_xor(mloc, 16));
      mloc = fmaxf(mloc, __shfl_xor(mloc, 32));
      const float mn = fmaxf(mprev, mloc);
      const float alpha = exp2f(mprev - mn);
      float ps = 0.f;
#pragma unroll
      for(int ns=0;ns<4;ns++)
#pragma unroll
        for(int r=0;r<4;r++){
          float p = exp2f(sc[ns][r] - mn);
          sc[ns][r] = p;
          ps += p;
        }
      ps += __shfl_xor(ps, 16);
      ps += __shfl_xor(ps, 32);
      lsum = lsum*alpha + ps;
      mprev = mn;

      // P -> per-wave LDS in A-layout: row q=fq, cols kv
#pragma unroll
      for(int ns=0;ns<4;ns++){
        u32 p01 = (u32)f2bf(sc[ns][0]) | ((u32)f2bf(sc[ns][1])<<16);
        u32 p23 = (u32)f2bf(sc[ns][2]) | ((u32)f2bf(sc[ns][3])<<16);
        uint2 pk; pk.x = p01; pk.y = p23;
        *(uint2*)&Pw[fq*72 + ns*16 + gq*4] = pk;
      }
      // rescale O rows (row q = gq*4+r)
      float alphaO[4];
#pragma unroll
      for(int r=0;r<4;r++) alphaO[r] = __shfl(alpha, gq*4 + r);
#pragma unroll
      for(int hs=0;hs<8;hs++)
#pragma unroll
        for(int r=0;r<4;r++) oacc[hs][r] *= alphaO[r];
      __builtin_amdgcn_s_waitcnt(0xC07F);  // lgkmcnt(0): P visible to own wave

      // O += P · V  (V frags from global, L2-resident after swizzle)
#pragma unroll
      for(int cc=0;cc<2;cc++){
        short8 pa = *(const short8*)&Pw[fq*72 + cc*32 + gq*8];
#pragma unroll
        for(int hs=0;hs<8;hs++){
          short8 vb = *(const short8*)(vbase + (size_t)(hs*16 + fq)*2048 + kt*64 + cc*32 + gq*8);
          oacc[hs] = mfma16(pa, vb, oacc[hs]);
        }
      }
    }
    const float inv = 1.f / lsum;
    float invO[4];
#pragma unroll
    for(int r=0;r<4;r++) invO[r] = __shfl(inv, gq*4 + r);
#pragma unroll
    for(int hs=0;hs<8;hs++)
#pragma unroll
      for(int r=0;r<4;r++){
        const int qi = qt*64 + wv*16 + gq*4 + r;
        attn[(((size_t)(b*2048 + qi))*16 + h)*128 + hs*16 + fq] = f2bf(oacc[hs][r]*invO[r]);
      }
  }
}

extern "C" void kernel_launch(void* const* d_in, const int* in_sizes, int n_in,
                              void* d_out, int out_size, void* d_ws, size_t ws_size,
                              hipStream_t stream){
  const float* x    = (const float*)d_in[0];
  const float* wq   = (const float*)d_in[1];
  const float* wkva = (const float*)d_in[2];
  const float* kvsc = (const float*)d_in[3];
  const float* wkvb = (const float*)d_in[4];
  const float* wo   = (const float*)d_in[5];
  const int* pid  = (const int*)d_in[7];
  float* out = (float*)d_out;

  char* w = (char*)d_ws;
  size_t off = 0;
  auto alloc = [&](size_t bytes)->void*{
    void* p = (void*)(w + off);
    off += (bytes + 255) & ~(size_t)255;
    return p;
  };
  u16*   x_bf   = (u16*)alloc((size_t)4096*2048*2);
  u16*   wq_t   = (u16*)alloc((size_t)4096*2048*2);
  u16*   wkva_t = (u16*)alloc((size_t)640*2048*2);
  u16*   wkvb_t = (u16*)alloc((size_t)2048*512*2);
  u16*   wo_t   = (u16*)alloc((size_t)2048*2048*2);
  float* cosT   = (float*)alloc((size_t)2048*64*4);
  float* sinT   = (float*)alloc((size_t)2048*64*4);
  u16*   q_raw  = (u16*)alloc((size_t)4096*4096*2);
  float* kvf    = (float*)alloc((size_t)4096*640*4);
  u16*   kv_cn  = (u16*)alloc((size_t)4096*512*2);
  u16*   k_pe   = (u16*)alloc((size_t)4096*128*2);
  u16*   kvb    = (u16*)alloc((size_t)4096*2048*2);
  u16*   q_fin  = (u16*)alloc((size_t)4096*4096*2);
  u16*   k_full = (u16*)alloc((size_t)2*8*2048*256*2);
  u16*   v_t    = (u16*)alloc((size_t)2*8*128*2048*2);
  u16*   attn   = (u16*)alloc((size_t)4096*2048*2);

  k_f2b<<<8192, 256, 0, stream>>>(x, x_bf, (size_t)4096*2048);
  k_transpose<<<dim3(128, 64), dim3(32,8), 0, stream>>>(wq,   wq_t,   2048, 4096);
  k_transpose<<<dim3(20,  64), dim3(32,8), 0, stream>>>(wkva, wkva_t, 2048, 640);
  k_transpose<<<dim3(64,  16), dim3(32,8), 0, stream>>>(wkvb, wkvb_t, 512,  2048);
  k_transpose<<<dim3(64,  64), dim3(32,8), 0, stream>>>(wo,   wo_t,   2048, 2048);
  k_rope_table<<<512, 256, 0, stream>>>(cosT, sinT);

  k_gemm_bt<0><<<dim3(32, 32), 256, 0, stream>>>(x_bf, wq_t, q_raw, 4096, 4096, 2048);
  k_gemm_bt<1><<<dim3(5,  32), 256, 0, stream>>>(x_bf, wkva_t, kvf, 4096, 640, 2048);
  k_ln_rope<<<4096, 256, 0, stream>>>(kvf, kvsc, pid, cosT, sinT, kv_cn, k_pe);
  k_gemm_bt<0><<<dim3(16, 32), 256, 0, stream>>>(kv_cn, wkvb_t, kvb, 4096, 2048, 512);
  k_q_rope<<<4096, 256, 0, stream>>>(q_raw, pid, cosT, sinT, q_fin);
  k_build_k<<<4096, 256, 0, stream>>>(kvb, k_pe, k_full);
  k_v_t<<<dim3(64, 4, 16), dim3(32,8), 0, stream>>>(kvb, v_t);
  k_attn<<<512, 256, 0, stream>>>(q_fin, k_full, v_t, attn);
  k_gemm_bt<1><<<dim3(16, 32), 256, 0, stream>>>(attn, wo_t, out, 4096, 2048, 2048);
}